// Round 1
// baseline (204.549 us; speedup 1.0000x reference)
//
#include <hip/hip_runtime.h>
#include <hip/hip_bf16.h>

// Problem constants (query/key/value: [2, 16384, 8, 64] fp32)
//   out[(b*8+r), i, j] = softmax_j( 0.125 * sum_{h, s%8==r} q[b,s,h,i]*k[b,s,h,j] )
// value is dead (DCE'd in the reference under jit).
#define NB 2
#define NS 16384
#define NH 8
#define ND 64
#define BUCKETS 16          // NB * 8 residues
#define ROW_FLOATS 512      // NH*ND floats per s index (contiguous)

__device__ __forceinline__ void gload_lds16(const float* g, float* l) {
    __builtin_amdgcn_global_load_lds(
        (const __attribute__((address_space(1))) void*)g,
        (__attribute__((address_space(3))) void*)l,
        16 /*bytes per lane*/, 0 /*offset*/, 0 /*aux*/);
}

// ---------------- Stage 1: partial Gram tiles ----------------
// grid = BUCKETS * bpb blocks, 256 threads.
// Each block: bucket = (b, r), a contiguous range of s_hi (s = s_hi*8 + r),
// accumulates C_part[64][64] (4x4 per thread) and writes it to part[bid].
__global__ __launch_bounds__(256) void gram_partial(
    const float* __restrict__ Q, const float* __restrict__ K,
    float* __restrict__ part, int bpb, int shi_per_blk)
{
    const int bid    = blockIdx.x;
    const int bucket = bid / bpb;
    const int chunk  = bid % bpb;
    const int b      = bucket >> 3;
    const int r      = bucket & 7;

    const int tid  = threadIdx.x;
    const int lane = tid & 63;
    const int wv   = tid >> 6;          // 4 waves
    const int ty   = tid >> 4;          // 0..15 -> C rows ty*4..+3
    const int tx   = tid & 15;          // 0..15 -> C cols tx*4..+3

    __shared__ __align__(16) float sbuf[2][2 * ROW_FLOATS]; // [buf][q(512) | k(512)]

    float acc[4][4] = {};

    // staging roles: wave 0/1 -> q halves, wave 2/3 -> k halves
    const float* gten = (wv >= 2 ? K : Q) + (size_t)b * ((size_t)NS * ROW_FLOATS);
    const int half = (wv & 1);
    float* l0 = &sbuf[0][(wv >= 2 ? ROW_FLOATS : 0) + half * 256];
    float* l1 = &sbuf[1][(wv >= 2 ? ROW_FLOATS : 0) + half * 256];

    const int s0 = chunk * shi_per_blk;  // starting s_hi
    // float offset for chunk c: ((s0+c)*8 + r)*512 + half*256 + lane*4
    const float* gcur = gten + ((size_t)s0 * 4096 + (size_t)r * ROW_FLOATS
                                + half * 256 + lane * 4);
    // step between consecutive s_hi: 8*512 floats
    const size_t gstep = 4096;

    // prologue: fill buffer 0
    gload_lds16(gcur, l0);

    for (int c = 0; c < shi_per_blk; ++c) {
        if (c + 1 < shi_per_blk) {
            gload_lds16(gcur + gstep, (c & 1) ? l0 : l1);
        }
        gcur += gstep;
        __syncthreads();   // compiler drains vmcnt before s_barrier -> buf[c&1] ready

        const float* bq = &sbuf[c & 1][0];
        const float* bk = &sbuf[c & 1][ROW_FLOATS];
        #pragma unroll
        for (int tr = 0; tr < 8; ++tr) {     // 8 t-rows per s chunk (the 8 heads)
            const float4 qv = *(const float4*)(bq + tr * 64 + ty * 4);
            const float4 kv = *(const float4*)(bk + tr * 64 + tx * 4);
            const float qa[4] = {qv.x, qv.y, qv.z, qv.w};
            const float ka[4] = {kv.x, kv.y, kv.z, kv.w};
            #pragma unroll
            for (int ii = 0; ii < 4; ++ii)
                #pragma unroll
                for (int jj = 0; jj < 4; ++jj)
                    acc[ii][jj] += qa[ii] * ka[jj];
        }
        __syncthreads();   // everyone done reading buf[c&1] before it is overwritten
    }

    float* p = part + (size_t)bid * 4096;
    #pragma unroll
    for (int ii = 0; ii < 4; ++ii) {
        float4 v = make_float4(acc[ii][0], acc[ii][1], acc[ii][2], acc[ii][3]);
        *(float4*)(p + (ty * 4 + ii) * 64 + tx * 4) = v;
    }
}

// ---------------- Stage 2: reduce partials + fused row softmax ----------------
// grid = 16 buckets * 16 col-groups = 256 blocks, 256 threads.
// Block (g, cg) owns elements e = cg*256 + tid of bucket g's 4096 scores:
// exactly 4 full rows; each 64-lane wave holds one full row -> in-wave softmax.
__global__ __launch_bounds__(256) void reduce_softmax(
    const float* __restrict__ part, float* __restrict__ out, int bpb)
{
    const int g   = blockIdx.x >> 4;
    const int cg  = blockIdx.x & 15;
    const int tid = threadIdx.x;
    const int e   = cg * 256 + tid;      // element in [0,4096)

    const float* p = part + (size_t)g * bpb * 4096 + e;
    float s = 0.f;
    for (int k = 0; k < bpb; ++k) s += p[(size_t)k * 4096];
    s *= 0.125f;   // SCALE = 1/sqrt(64)

    // row softmax across the 64 lanes of this wave (one row per wave)
    float m = s;
    #pragma unroll
    for (int o = 32; o; o >>= 1) m = fmaxf(m, __shfl_xor(m, o));
    const float ex = __expf(s - m);
    float sum = ex;
    #pragma unroll
    for (int o = 32; o; o >>= 1) sum += __shfl_xor(sum, o);

    out[(size_t)g * 4096 + e] = ex / sum;
}

// ---------------- launch ----------------
extern "C" void kernel_launch(void* const* d_in, const int* in_sizes, int n_in,
                              void* d_out, int out_size, void* d_ws, size_t ws_size,
                              hipStream_t stream)
{
    const float* Q = (const float*)d_in[0];
    const float* K = (const float*)d_in[1];
    // d_in[2] (value) is dead in the reference -> never read.
    float* out  = (float*)d_out;
    float* part = (float*)d_ws;

    int bpb = 64;  // blocks per bucket; partials need 16*bpb*16KB of workspace
    while ((size_t)BUCKETS * bpb * 4096 * sizeof(float) > ws_size && bpb > 1) bpb >>= 1;
    const int shi_per_blk = 2048 / bpb;

    gram_partial<<<dim3(BUCKETS * bpb), dim3(256), 0, stream>>>(Q, K, part, bpb, shi_per_blk);
    reduce_softmax<<<dim3(256), dim3(256), 0, stream>>>(part, out, bpb);
}

// Round 4
// 189.437 us; speedup vs baseline: 1.0798x; 1.0798x over previous
//
#include <hip/hip_runtime.h>

// out[(b*8+r), i, j] = softmax_j( 0.125 * sum_{h, s%8==r} q[b,s,h,i]*k[b,s,h,j] )
// value input is dead (DCE'd under jit in the reference).
// q/k: [2, 16384, 8, 64] fp32. Row of 512 floats per s index is contiguous.
#define NS 16384
#define BUCKETS 16

__device__ __forceinline__ void gload_lds16(const float* g, float* l) {
    __builtin_amdgcn_global_load_lds(
        (const __attribute__((address_space(1))) void*)g,
        (__attribute__((address_space(3))) void*)l,
        16 /*bytes/lane*/, 0, 0);
}

// ---------------- Stage 1: partial Gram tiles ----------------
// grid = BUCKETS*bpb blocks, 256 threads. Block: bucket (b,r) + s_hi chunk.
// Per iteration: stage 4 s_hi (q 8KB + k 8KB) double-buffered via
// global_load_lds; prefetch is issued AFTER the barrier so it overlaps the
// compute phase instead of being drained immediately (round-1 bug).
__global__ __launch_bounds__(256) void gram_partial(
    const float* __restrict__ Q, const float* __restrict__ K,
    float* __restrict__ part, int bpb, int shi_per_blk)
{
    const int bid    = blockIdx.x;
    const int bucket = bid / bpb;
    const int chunk  = bid % bpb;
    const int b      = bucket >> 3;
    const int r      = bucket & 7;

    const int tid  = threadIdx.x;
    const int lane = tid & 63;
    const int wv   = tid >> 6;   // 4 waves
    const int ty   = tid >> 4;   // 0..15 -> C rows ty*4..+3
    const int tx   = tid & 15;   // 0..15 -> C cols tx*4..+3

    __shared__ __align__(16) float sbuf[2][4096];  // [buf][ q:4x512 | k:4x512 ]

    // wave w stages s_hi = (base + it*4 + w) rows of q and k (2 halves each)
    const float* gq = Q + (size_t)b * ((size_t)NS * 512)
                        + ((size_t)wv * 8 + r) * 512 + lane * 4;
    const float* gk = K + (size_t)b * ((size_t)NS * 512)
                        + ((size_t)wv * 8 + r) * 512 + lane * 4;
    const size_t base_off = (size_t)chunk * shi_per_blk * 4096;

    const int niter = shi_per_blk >> 2;   // 4 s_hi per iteration

    auto stage = [&](int it, int bufi) {
        const size_t off = base_off + (size_t)it * 16384;  // 4 s_hi * 4096 floats
        float* dq = &sbuf[bufi][wv * 512];
        float* dk = &sbuf[bufi][2048 + wv * 512];
        gload_lds16(gq + off, dq);
        gload_lds16(gq + off + 256, dq + 256);
        gload_lds16(gk + off, dk);
        gload_lds16(gk + off + 256, dk + 256);
    };

    float acc[4][4] = {};

    stage(0, 0);                    // prologue
    for (int it = 0; it < niter; ++it) {
        __syncthreads();            // drains the stage issued LAST iteration
        if (it + 1 < niter) stage(it + 1, (it + 1) & 1);  // overlaps compute below
        const float* bq = &sbuf[it & 1][0];
        const float* bk = &sbuf[it & 1][2048];
        #pragma unroll
        for (int tr = 0; tr < 32; ++tr) {   // 4 s_hi * 8 heads
            const float4 qv = *(const float4*)(bq + tr * 64 + ty * 4);
            const float4 kv = *(const float4*)(bk + tr * 64 + tx * 4);
            const float qa[4] = {qv.x, qv.y, qv.z, qv.w};
            const float ka[4] = {kv.x, kv.y, kv.z, kv.w};
            #pragma unroll
            for (int ii = 0; ii < 4; ++ii)
                #pragma unroll
                for (int jj = 0; jj < 4; ++jj)
                    acc[ii][jj] += qa[ii] * ka[jj];
        }
    }

    float* p = part + (size_t)bid * 4096;
    #pragma unroll
    for (int ii = 0; ii < 4; ++ii) {
        float4 v = make_float4(acc[ii][0], acc[ii][1], acc[ii][2], acc[ii][3]);
        *(float4*)(p + (ty * 4 + ii) * 64 + tx * 4) = v;
    }
}

// ---------------- Stage 2: reduce partials + fused row softmax ----------------
// grid = 16 buckets * 64 rows = 1024 blocks, 256 threads.
// Thread (c = tid&63, sl = tid>>6): sums `slices` partials (independent,
// coalesced 256B/wave loads), LDS cross-wave reduce, in-wave softmax.
__global__ __launch_bounds__(256) void reduce_softmax(
    const float* __restrict__ part, float* __restrict__ out, int slices)
{
    const int g   = blockIdx.x >> 6;
    const int row = blockIdx.x & 63;
    const int c   = threadIdx.x & 63;
    const int sl  = threadIdx.x >> 6;

    const float* p = part + (size_t)(g * (slices * 4) + sl * slices) * 4096
                          + row * 64 + c;
    float s = 0.f;
    #pragma unroll 4
    for (int k = 0; k < slices; ++k) s += p[(size_t)k * 4096];

    __shared__ float red[4][64];
    red[sl][c] = s;
    __syncthreads();
    if (sl == 0) {
        float v = (red[0][c] + red[1][c]) + (red[2][c] + red[3][c]);
        v *= 0.125f;   // SCALE = 1/sqrt(64)
        float m = v;
        #pragma unroll
        for (int o = 32; o; o >>= 1) m = fmaxf(m, __shfl_xor(m, o));
        const float e = __expf(v - m);
        float sum = e;
        #pragma unroll
        for (int o = 32; o; o >>= 1) sum += __shfl_xor(sum, o);
        out[(size_t)g * 4096 + row * 64 + c] = e / sum;
    }
}

// ---------------- launch ----------------
extern "C" void kernel_launch(void* const* d_in, const int* in_sizes, int n_in,
                              void* d_out, int out_size, void* d_ws, size_t ws_size,
                              hipStream_t stream)
{
    const float* Q = (const float*)d_in[0];
    const float* K = (const float*)d_in[1];
    // d_in[2] (value) is dead in the reference -> never read.
    float* out  = (float*)d_out;
    float* part = (float*)d_ws;

    int bpb = 64;   // 16*64 blocks, 16.7 MB workspace (fit verified round 1)
    while ((size_t)BUCKETS * bpb * 4096 * sizeof(float) > ws_size && bpb > 4) bpb >>= 1;
    const int shi_per_blk = 2048 / bpb;

    gram_partial<<<dim3(BUCKETS * bpb), dim3(256), 0, stream>>>(Q, K, part, bpb, shi_per_blk);
    reduce_softmax<<<dim3(1024), dim3(256), 0, stream>>>(part, out, bpb / 4);
}